// Round 4
// baseline (557.181 us; speedup 1.0000x reference)
//
#include <hip/hip_runtime.h>
#include <hip/hip_bf16.h>

typedef __attribute__((ext_vector_type(8))) __bf16 bf16x8;
typedef __attribute__((ext_vector_type(2))) __bf16 bf16x2;
typedef __attribute__((ext_vector_type(4))) float floatx4;
typedef __attribute__((ext_vector_type(2))) unsigned int uint2v;

#define DEV static __device__ __forceinline__

typedef __attribute__((address_space(1))) const unsigned int gu32;
typedef __attribute__((address_space(3))) unsigned int lu32;

DEV void dma16(const void* g, void* l) {
  // async global->LDS, 16B/lane; LDS dst = wave-uniform base + lane*16
  __builtin_amdgcn_global_load_lds((gu32*)g, (lu32*)l, 16, 0, 0);
}

DEV unsigned short f2bf(float f) {
  unsigned int u = __float_as_uint(f);
  u += 0x7fffu + ((u >> 16) & 1u);   // round-to-nearest-even
  return (unsigned short)(u >> 16);
}

DEV unsigned int pk_bf16(float a, float b) {
#if __has_builtin(__builtin_amdgcn_cvt_pk_bf16_f32)
  bf16x2 r = __builtin_amdgcn_cvt_pk_bf16_f32(a, b);
  union { bf16x2 v; unsigned int u; } c; c.v = r;
  return c.u;
#else
  return (unsigned int)f2bf(a) | ((unsigned int)f2bf(b) << 16);
#endif
}

DEV float wred_sum(float v) {
#pragma unroll
  for (int o = 32; o > 0; o >>= 1) v += __shfl_xor(v, o, 64);
  return v;
}

DEV floatx4 mfma32(bf16x8 a, bf16x8 b, floatx4 c) {
  return __builtin_amdgcn_mfma_f32_16x16x32_bf16(a, b, c, 0, 0, 0);
}

#if __has_builtin(__builtin_amdgcn_permlane32_swap) && __has_builtin(__builtin_amdgcn_permlane16_swap)
#define HAS_PLSWAP 1
DEV void p32sw(unsigned int& a, unsigned int& b) {
  uint2v r = __builtin_amdgcn_permlane32_swap(a, b, false, false);
  a = r[0]; b = r[1];
}
DEV void p16sw(unsigned int& a, unsigned int& b) {
  uint2v r = __builtin_amdgcn_permlane16_swap(a, b, false, false);
  a = r[0]; b = r[1];
}
#endif

// ---------------- K1: emb = silu(t_emb) @ W_ada^T + b_ada  -> [2][4096] f32
__global__ void ada_kernel(const float* __restrict__ t_emb, const float* __restrict__ W_ada,
                           const float* __restrict__ b_ada, float* __restrict__ emb) {
  int w = threadIdx.x >> 6, lane = threadIdx.x & 63;
  int gid = blockIdx.x * 4 + w;          // 0..8191
  int b = gid >> 12, n = gid & 4095;
  const float* te = t_emb + (size_t)b * 1280;
  const float* wr = W_ada + (size_t)n * 1280;
  float acc = 0.f;
#pragma unroll
  for (int i = 0; i < 20; ++i) {
    int t = lane + i * 64;
    float x = te[t];
    float s = x / (1.f + __expf(-x));
    acc += s * wr[t];
  }
  acc = wred_sum(acc);
  if (lane == 0) emb[gid] = acc + b_ada[n];
}

// ---------------- K2: LayerNorm(ip) * (1+scale) + shift -> bf16 ip_n [1024][2048]
__global__ void ln_mod_kernel(const float* __restrict__ ip, const float* __restrict__ emb,
                              unsigned short* __restrict__ ipn) {
  int row = blockIdx.x;            // b*512 + l
  int b = row >> 9;
  const float* x = ip + (size_t)row * 2048;
  float xv[8];
  float s1 = 0.f, s2 = 0.f;
#pragma unroll
  for (int i = 0; i < 8; ++i) {
    float v = x[threadIdx.x + i * 256];
    xv[i] = v; s1 += v; s2 += v * v;
  }
  s1 = wred_sum(s1); s2 = wred_sum(s2);
  __shared__ float r1[4], r2[4];
  int w = threadIdx.x >> 6, lane = threadIdx.x & 63;
  if (lane == 0) { r1[w] = s1; r2[w] = s2; }
  __syncthreads();
  s1 = r1[0] + r1[1] + r1[2] + r1[3];
  s2 = r2[0] + r2[1] + r2[2] + r2[3];
  float mu = s1 * (1.f / 2048.f);
  float var = s2 * (1.f / 2048.f) - mu * mu;
  float rs = rsqrtf(var + 1e-6f);
  const float* sh = emb + (size_t)b * 4096;
  unsigned short* y = ipn + (size_t)row * 2048;
#pragma unroll
  for (int i = 0; i < 8; ++i) {
    int d = threadIdx.x + i * 256;
    float v = (xv[i] - mu) * rs;
    v = v * (1.f + sh[2048 + d]) + sh[d];
    y[d] = f2bf(v);
  }
}

// ---------------- K3: convert W_k_ip / W_v_ip fp32 -> bf16
struct us4 { unsigned short a, b, c, d; };
__global__ void cvtw_kernel(const float* __restrict__ wk, const float* __restrict__ wv,
                            unsigned short* __restrict__ wk16, unsigned short* __restrict__ wv16) {
  size_t i = ((size_t)blockIdx.x * 256 + threadIdx.x) * 4;
  float4 a = *(const float4*)(wk + i);
  float4 b = *(const float4*)(wv + i);
  us4 oa = { f2bf(a.x), f2bf(a.y), f2bf(a.z), f2bf(a.w) };
  us4 ob = { f2bf(b.x), f2bf(b.y), f2bf(b.z), f2bf(b.w) };
  *(us4*)(wk16 + i) = oa;
  *(us4*)(wv16 + i) = ob;
}

// ---------------- K4: C[1024,2048] = A[1024,2048]bf16 @ W[2048,2048]^T bf16 -> f32
__global__ __launch_bounds__(256) void proj_gemm(const unsigned short* __restrict__ A,
    const unsigned short* __restrict__ Wk, const unsigned short* __restrict__ Wv,
    float* __restrict__ Ck, float* __restrict__ Cv) {
  const unsigned short* Bm = blockIdx.z ? Wv : Wk;
  float* C = blockIdx.z ? Cv : Ck;
  int n0 = blockIdx.x * 64, m0 = blockIdx.y * 128;
  __shared__ __align__(16) unsigned short As[128 * 72];
  __shared__ __align__(16) unsigned short Bs[64 * 72];
  int tid = threadIdx.x, w = tid >> 6, lane = tid & 63, quad = lane >> 4, l16 = lane & 15;
  floatx4 acc[2][4];
#pragma unroll
  for (int i = 0; i < 2; ++i)
#pragma unroll
    for (int j = 0; j < 4; ++j) { floatx4 z = {0.f, 0.f, 0.f, 0.f}; acc[i][j] = z; }
  for (int kk = 0; kk < 2048; kk += 64) {
#pragma unroll
    for (int it = 0; it < 4; ++it) {
      int idx = tid + it * 256;
      int row = idx >> 3, chk = idx & 7;
      *(uint4*)&As[row * 72 + chk * 8] = *(const uint4*)&A[(size_t)(m0 + row) * 2048 + kk + chk * 8];
    }
#pragma unroll
    for (int it = 0; it < 2; ++it) {
      int idx = tid + it * 256;
      int row = idx >> 3, chk = idx & 7;
      *(uint4*)&Bs[row * 72 + chk * 8] = *(const uint4*)&Bm[(size_t)(n0 + row) * 2048 + kk + chk * 8];
    }
    __syncthreads();
#pragma unroll
    for (int c = 0; c < 2; ++c) {
      bf16x8 a0 = *(const bf16x8*)&As[(w * 32 + l16) * 72 + quad * 8 + c * 32];
      bf16x8 a1 = *(const bf16x8*)&As[(w * 32 + 16 + l16) * 72 + quad * 8 + c * 32];
#pragma unroll
      for (int nt = 0; nt < 4; ++nt) {
        bf16x8 bb = *(const bf16x8*)&Bs[(nt * 16 + l16) * 72 + quad * 8 + c * 32];
        acc[0][nt] = mfma32(a0, bb, acc[0][nt]);
        acc[1][nt] = mfma32(a1, bb, acc[1][nt]);
      }
    }
    __syncthreads();
  }
#pragma unroll
  for (int rt = 0; rt < 2; ++rt)
#pragma unroll
    for (int nt = 0; nt < 4; ++nt)
#pragma unroll
      for (int r = 0; r < 4; ++r)
        C[(size_t)(m0 + w * 32 + rt * 16 + quad * 4 + r) * 2048 + n0 + nt * 16 + l16] = acc[rt][nt][r];
}

// ---------------- K5: Kcat [bh][2560][128] (rms, 16B-chunk XOR-swizzled per row)
//                      Vrec [bh][mt=40][16 records][64 lanes][8 bf16]
//   V is emitted as ready-made PV A-fragments: record r=(dt*2+mc), lane
//   (quad,l16) holds V^T[dt*16+l16][mc*32+quad*8 .. +7]. attn reads one
//   coalesced 1-KB global load per (dt,mc) -- V never touches attn's LDS.
__global__ __launch_bounds__(256) void kv_build(const float* __restrict__ img_key, const float* __restrict__ img_value,
                         const float* __restrict__ ipk, const float* __restrict__ ipv,
                         const float* __restrict__ w_k, const float* __restrict__ w_ipk,
                         unsigned short* __restrict__ Kc, unsigned short* __restrict__ Vrec) {
  int bh = blockIdx.x;                 // 0..31
  int mt = blockIdx.y;                 // 0..39
  int b = bh >> 4, hh = bh & 15;
  int m0 = mt * 64;
  __shared__ __align__(16) unsigned short Vs[64 * 132];
  int tid = threadIdx.x;
  int mrow = tid >> 2, dq = tid & 3;   // 64 rows x 4 quarters of d
  int m = m0 + mrow;
  size_t base;
  const float* wsrc;
  const float *ksrc, *vsrc;
  if (m < 2048) {
    base = (size_t)(b * 2048 + m) * 2048 + hh * 128;
    ksrc = img_key + base; vsrc = img_value + base; wsrc = w_k;
  } else {
    base = (size_t)(b * 512 + (m - 2048)) * 2048 + hh * 128;
    ksrc = ipk + base; vsrc = ipv + base; wsrc = w_ipk;
  }
  // K: load 32 d-values, rms over 4 lanes sharing the row, write swizzled bf16
  float kvv[32]; float ss = 0.f;
  const float4* k4 = (const float4*)ksrc;
#pragma unroll
  for (int i = 0; i < 8; ++i) {
    float4 x = k4[dq * 8 + i];
    kvv[i * 4 + 0] = x.x; kvv[i * 4 + 1] = x.y; kvv[i * 4 + 2] = x.z; kvv[i * 4 + 3] = x.w;
    ss += x.x * x.x + x.y * x.y + x.z * x.z + x.w * x.w;
  }
  ss += __shfl_xor(ss, 1, 64);
  ss += __shfl_xor(ss, 2, 64);
  float rs = rsqrtf(ss * (1.f / 128.f) + 1e-6f);
  unsigned short kb[32];
#pragma unroll
  for (int j = 0; j < 32; ++j) kb[j] = f2bf(kvv[j] * rs * wsrc[dq * 32 + j]);
  uint4* kdst = (uint4*)&Kc[((size_t)bh * 2560 + m) * 128];
#pragma unroll
  for (int i = 0; i < 4; ++i) kdst[(dq * 4 + i) ^ (m & 7)] = ((const uint4*)kb)[i];
  // V: to LDS as bf16 [m][d] (stride 132), then frag-records out (coalesced)
  const float4* v4 = (const float4*)vsrc;
#pragma unroll
  for (int i = 0; i < 8; ++i) {
    float4 x = v4[dq * 8 + i];
    us4 p = { f2bf(x.x), f2bf(x.y), f2bf(x.z), f2bf(x.w) };
    *(us4*)&Vs[mrow * 132 + dq * 32 + i * 4] = p;
  }
  __syncthreads();
  // thread handles lane-slot (tid&63) of records r = (tid>>6) + 4*i
  int lslot = tid & 63;
  unsigned short* tb = Vrec + ((size_t)(bh * 40 + mt)) * 8192;
#pragma unroll
  for (int i = 0; i < 4; ++i) {
    int r = (tid >> 6) + 4 * i;          // 0..15 = dt*2+mc
    int dcol = (r >> 1) * 16 + (lslot & 15);
    int mrow2 = (r & 1) * 32 + (lslot >> 4) * 8;
    unsigned short ob[8];
#pragma unroll
    for (int j = 0; j < 8; ++j) ob[j] = Vs[(mrow2 + j) * 132 + dcol];
    *(uint4*)&tb[r * 512 + lslot * 8] = *(const uint4*)ob;
  }
}

// ---------------- K7: flash attention, transposed-S formulation.
// Round-4 restructure (occupancy): V comes straight from global as
// pre-built A-frag records (1-KB coalesced load per (dt,mc)); only K is
// staged in LDS (double-buffered 2x16KB = 32 KB) -> 4 blocks/CU at
// VGPR<=128 (__launch_bounds__(256,4)). QK^T runs per-32m-chunk to keep
// sacc live range at 16 regs. S^T = K*Q^T; P transposed in-register
// (permlane32/16 swaps) to the K=32 B-frag layout; O^T = Vrec * P.
__global__ __launch_bounds__(256, 4) void attn_kernel(const float* __restrict__ Qf,
    const float* __restrict__ w_q,
    const unsigned short* __restrict__ Kc, const unsigned short* __restrict__ Vrec,
    float* __restrict__ out) {
  const float SCL = 0.12751744f;   // (1/sqrt(128)) * log2(e)
  const float FM = 17.0f;          // fixed softmax max (score*SCL bounded by 16.4)
  // XCD-locality remap: XCD = blockIdx % 8 (round-robin dispatch)
  int n = blockIdx.x;              // 0..511
  int xcd = n & 7, jj = n >> 3;    // jj 0..63
  int bh = xcd * 4 + (jj >> 4);    // 4 consecutive bh per XCD
  int qt2 = jj & 15;               // 0..15, 128 q-rows each
  int b = bh >> 4, hh = bh & 15;
  int tid = threadIdx.x, w = tid >> 6, lane = tid & 63, quad = lane >> 4, l16 = lane & 15;
  int xr = l16 & 7;

  __shared__ __align__(16) unsigned char smem[32768];    // 2x Kt 16K

  int q0 = qt2 * 128;

  // ---- Q: load f32, RMS-norm, pack to B bf16 fragments (2 q-tiles/wave)
  bf16x8 aq[2][4];
#pragma unroll
  for (int qtl = 0; qtl < 2; ++qtl) {
    int qrow = q0 + w * 32 + qtl * 16 + l16;
    const float* src = Qf + ((size_t)(b * 2048 + qrow)) * 2048 + hh * 128;
    float xs[32]; float ss = 0.f;
#pragma unroll
    for (int c = 0; c < 4; ++c) {
      float4 a = *(const float4*)&src[quad * 8 + c * 32];
      float4 b2 = *(const float4*)&src[quad * 8 + c * 32 + 4];
      xs[c * 8 + 0] = a.x;  xs[c * 8 + 1] = a.y;  xs[c * 8 + 2] = a.z;  xs[c * 8 + 3] = a.w;
      xs[c * 8 + 4] = b2.x; xs[c * 8 + 5] = b2.y; xs[c * 8 + 6] = b2.z; xs[c * 8 + 7] = b2.w;
      ss += a.x * a.x + a.y * a.y + a.z * a.z + a.w * a.w
          + b2.x * b2.x + b2.y * b2.y + b2.z * b2.z + b2.w * b2.w;
    }
    ss += __shfl_xor(ss, 16, 64);
    ss += __shfl_xor(ss, 32, 64);
    float rs = rsqrtf(ss * (1.f / 128.f) + 1e-6f);
#pragma unroll
    for (int c = 0; c < 4; ++c) {
      float4 wa = *(const float4*)&w_q[quad * 8 + c * 32];
      float4 wb = *(const float4*)&w_q[quad * 8 + c * 32 + 4];
      union { unsigned int u[4]; bf16x8 v; } pk;
      pk.u[0] = pk_bf16(xs[c * 8 + 0] * rs * wa.x, xs[c * 8 + 1] * rs * wa.y);
      pk.u[1] = pk_bf16(xs[c * 8 + 2] * rs * wa.z, xs[c * 8 + 3] * rs * wa.w);
      pk.u[2] = pk_bf16(xs[c * 8 + 4] * rs * wb.x, xs[c * 8 + 5] * rs * wb.y);
      pk.u[3] = pk_bf16(xs[c * 8 + 6] * rs * wb.z, xs[c * 8 + 7] * rs * wb.w);
      aq[qtl][c] = pk.v;
    }
  }

  const unsigned short* Kb = Kc + (size_t)bh * 2560 * 128;
  const unsigned short* Vb = Vrec + (size_t)bh * 40 * 8192;

  floatx4 acc[2][8];
#pragma unroll
  for (int i = 0; i < 2; ++i)
#pragma unroll
    for (int j = 0; j < 8; ++j) { floatx4 z = {0.f, 0.f, 0.f, 0.f}; acc[i][j] = z; }
  float rsum[2] = {0.f, 0.f};

  int seg = w * 4;
  auto stage = [&](int buf, int t) {
    const unsigned short* Ksrc = Kb + (size_t)t * 8192;
    unsigned short* Kt = (unsigned short*)(smem + buf * 16384);
#pragma unroll
    for (int j = 0; j < 4; ++j) {
      int off = (seg + j) * 512 + lane * 8;
      dma16(Ksrc + off, Kt + (seg + j) * 512);
    }
  };

  stage(0, 0);
  __syncthreads();

  for (int t = 0; t < 40; ++t) {
    int cur = t & 1;
    if (t < 39) stage(cur ^ 1, t + 1);   // issue next tile's K loads
    const unsigned short* Kt = (const unsigned short*)(smem + cur * 16384);
    const unsigned short* Vr = Vb + (size_t)t * 8192;

    // S^T = K·Q^T per 32-m chunk; softmax+transpose immediately (sacc live = 16 regs)
    union { unsigned int u[4]; bf16x8 v; } pf[2][2];   // [mchunk][qtl]
#pragma unroll
    for (int mc = 0; mc < 2; ++mc) {
      floatx4 sacc[2][2];
#pragma unroll
      for (int i = 0; i < 2; ++i)
#pragma unroll
        for (int j = 0; j < 2; ++j) { floatx4 z = {0.f, 0.f, 0.f, 0.f}; sacc[i][j] = z; }
#pragma unroll
      for (int ms2 = 0; ms2 < 2; ++ms2) {
        int krow = ((mc * 2 + ms2) * 16 + l16) * 128;
#pragma unroll
        for (int c = 0; c < 4; ++c) {
          bf16x8 bk = *(const bf16x8*)&Kt[krow + ((quad + c * 4) ^ xr) * 8];
          sacc[ms2][0] = mfma32(bk, aq[0][c], sacc[ms2][0]);
          sacc[ms2][1] = mfma32(bk, aq[1][c], sacc[ms2][1]);
        }
      }
#pragma unroll
      for (int qtl = 0; qtl < 2; ++qtl) {
        float pA[4], pB[4];
#pragma unroll
        for (int r = 0; r < 4; ++r) {
          pA[r] = __builtin_amdgcn_exp2f(fmaf(sacc[0][qtl][r], SCL, -FM));
          pB[r] = __builtin_amdgcn_exp2f(fmaf(sacc[1][qtl][r], SCL, -FM));
        }
        rsum[qtl] += (pA[0] + pA[1]) + (pA[2] + pA[3])
                   + (pB[0] + pB[1]) + (pB[2] + pB[3]);
        // R_r@quad holds m-pair rho = 8*(r>>1) + 2*quad + (r&1)
        unsigned int R0 = pk_bf16(pA[0], pA[1]);
        unsigned int R1 = pk_bf16(pA[2], pA[3]);
        unsigned int R2 = pk_bf16(pB[0], pB[1]);
        unsigned int R3 = pk_bf16(pB[2], pB[3]);
#ifdef HAS_PLSWAP
        // transpose: target T_j@quad = rho 4*quad + j  (k = quad*8+2j,+1)
        p32sw(R0, R2);   // R0=(0,2,8,10)   R2=(4,6,12,14)
        p32sw(R1, R3);   // R1=(1,3,9,11)   R3=(5,7,13,15)
        p16sw(R0, R2);   // R0=(0,4,8,12)=T0  R2=(2,6,10,14)=T2
        p16sw(R1, R3);   // R1=(1,5,9,13)=T1  R3=(3,7,11,15)=T3
        pf[mc][qtl].u[0] = R0; pf[mc][qtl].u[1] = R1;
        pf[mc][qtl].u[2] = R2; pf[mc][qtl].u[3] = R3;
#else
        // fallback: T_j <- R_{2*(quad>>1)+(j&1)} @ lane (2*(quad&1)+(j>>1))*16+l16
        int base = ((quad & 1) * 2) * 16 + l16;
        int base2 = base + 16;
        unsigned int a0 = __shfl((int)R0, base, 64),  b0 = __shfl((int)R2, base, 64);
        unsigned int a1 = __shfl((int)R1, base, 64),  b1 = __shfl((int)R3, base, 64);
        unsigned int a2 = __shfl((int)R0, base2, 64), b2 = __shfl((int)R2, base2, 64);
        unsigned int a3 = __shfl((int)R1, base2, 64), b3 = __shfl((int)R3, base2, 64);
        bool hi = (quad >> 1) != 0;
        pf[mc][qtl].u[0] = hi ? b0 : a0;
        pf[mc][qtl].u[1] = hi ? b1 : a1;
        pf[mc][qtl].u[2] = hi ? b2 : a2;
        pf[mc][qtl].u[3] = hi ? b3 : a3;
#endif
      }
    }

    // O^T += V·P : A-frag = direct coalesced 1-KB record loads, K=32
#pragma unroll
    for (int dt = 0; dt < 8; ++dt) {
      bf16x8 va0 = *(const bf16x8*)&Vr[(dt * 2 + 0) * 512 + lane * 8];
      bf16x8 va1 = *(const bf16x8*)&Vr[(dt * 2 + 1) * 512 + lane * 8];
      acc[0][dt] = mfma32(va0, pf[0][0].v, acc[0][dt]);
      acc[1][dt] = mfma32(va0, pf[0][1].v, acc[1][dt]);
      acc[0][dt] = mfma32(va1, pf[1][0].v, acc[0][dt]);
      acc[1][dt] = mfma32(va1, pf[1][1].v, acc[1][dt]);
    }
    __syncthreads();   // drains vmcnt: next tile's K loads completed during compute
  }

  // ---- epilogue: rsum complete per wave after quad reduction; direct write
  rsum[0] += __shfl_xor(rsum[0], 16, 64); rsum[0] += __shfl_xor(rsum[0], 32, 64);
  rsum[1] += __shfl_xor(rsum[1], 16, 64); rsum[1] += __shfl_xor(rsum[1], 32, 64);
#pragma unroll
  for (int qtl = 0; qtl < 2; ++qtl) {
    float inv = 1.f / rsum[qtl];
    int qrow = q0 + w * 32 + qtl * 16 + l16;
    float* orow = out + ((size_t)(b * 2048 + qrow)) * 2048 + hh * 128;
#pragma unroll
    for (int dt = 0; dt < 8; ++dt) {
      floatx4 r = acc[qtl][dt] * inv;
      *(floatx4*)&orow[dt * 16 + quad * 4] = r;
    }
  }
}

extern "C" void kernel_launch(void* const* d_in, const int* in_sizes, int n_in,
                              void* d_out, int out_size, void* d_ws, size_t ws_size,
                              hipStream_t stream) {
  const float* ip    = (const float*)d_in[0];
  const float* q     = (const float*)d_in[1];
  const float* k     = (const float*)d_in[2];
  const float* v     = (const float*)d_in[3];
  const float* temb  = (const float*)d_in[4];
  const float* wada  = (const float*)d_in[5];
  const float* bada  = (const float*)d_in[6];
  const float* wkip  = (const float*)d_in[7];
  const float* wvip  = (const float*)d_in[8];
  const float* w_q   = (const float*)d_in[9];
  const float* w_k   = (const float*)d_in[10];
  const float* w_ipk = (const float*)d_in[11];
  float* out = (float*)d_out;
  char* ws = (char*)d_ws;

  // Lifetime-overlapped workspace layout (75.5 MB total):
  //   emb[0,32K) ipn[32K,4.2M) wk16[4.2M,12.6M) wv16[12.6M,21.0M)  (dead after proj_gemm)
  //   Kcat[16.7M,37.7M) Vrec[37.7M,58.7M)
  //   ipk[58.7M,67.1M) ipv[67.1M,75.5M)
  float* emb           = (float*)(ws + 0);
  unsigned short* ipn  = (unsigned short*)(ws + 32768);
  unsigned short* wk16 = (unsigned short*)(ws + 4227072);
  unsigned short* wv16 = (unsigned short*)(ws + 12615680);
  unsigned short* Kcat = (unsigned short*)(ws + 16777216);
  unsigned short* Vrec = (unsigned short*)(ws + 37748736);
  float* ipk           = (float*)(ws + 58720256);
  float* ipv           = (float*)(ws + 67108864);

  ada_kernel<<<dim3(2048), dim3(256), 0, stream>>>(temb, wada, bada, emb);
  ln_mod_kernel<<<dim3(1024), dim3(256), 0, stream>>>(ip, emb, ipn);
  cvtw_kernel<<<dim3(4096), dim3(256), 0, stream>>>(wkip, wvip, wk16, wv16);
  proj_gemm<<<dim3(32, 8, 2), dim3(256), 0, stream>>>(ipn, wk16, wv16, ipk, ipv);
  kv_build<<<dim3(32, 40), dim3(256), 0, stream>>>(k, v, ipk, ipv, w_k, w_ipk, Kcat, Vrec);
  attn_kernel<<<dim3(512), dim3(256), 0, stream>>>(q, w_q, Kcat, Vrec, out);
}

// Round 5
// 427.573 us; speedup vs baseline: 1.3031x; 1.3031x over previous
//
#include <hip/hip_runtime.h>
#include <hip/hip_bf16.h>

typedef __attribute__((ext_vector_type(8))) __bf16 bf16x8;
typedef __attribute__((ext_vector_type(2))) __bf16 bf16x2;
typedef __attribute__((ext_vector_type(4))) float floatx4;
typedef __attribute__((ext_vector_type(2))) unsigned int uint2v;

#define DEV static __device__ __forceinline__

typedef __attribute__((address_space(1))) const unsigned int gu32;
typedef __attribute__((address_space(3))) unsigned int lu32;

DEV void dma16(const void* g, void* l) {
  // async global->LDS, 16B/lane; LDS dst = wave-uniform base + lane*16
  __builtin_amdgcn_global_load_lds((gu32*)g, (lu32*)l, 16, 0, 0);
}

DEV unsigned short f2bf(float f) {
  unsigned int u = __float_as_uint(f);
  u += 0x7fffu + ((u >> 16) & 1u);   // round-to-nearest-even
  return (unsigned short)(u >> 16);
}

DEV unsigned int pk_bf16(float a, float b) {
#if __has_builtin(__builtin_amdgcn_cvt_pk_bf16_f32)
  bf16x2 r = __builtin_amdgcn_cvt_pk_bf16_f32(a, b);
  union { bf16x2 v; unsigned int u; } c; c.v = r;
  return c.u;
#else
  return (unsigned int)f2bf(a) | ((unsigned int)f2bf(b) << 16);
#endif
}

DEV float wred_sum(float v) {
#pragma unroll
  for (int o = 32; o > 0; o >>= 1) v += __shfl_xor(v, o, 64);
  return v;
}

DEV floatx4 mfma32(bf16x8 a, bf16x8 b, floatx4 c) {
  return __builtin_amdgcn_mfma_f32_16x16x32_bf16(a, b, c, 0, 0, 0);
}

#if __has_builtin(__builtin_amdgcn_permlane32_swap) && __has_builtin(__builtin_amdgcn_permlane16_swap)
#define HAS_PLSWAP 1
DEV void p32sw(unsigned int& a, unsigned int& b) {
  uint2v r = __builtin_amdgcn_permlane32_swap(a, b, false, false);
  a = r[0]; b = r[1];
}
DEV void p16sw(unsigned int& a, unsigned int& b) {
  uint2v r = __builtin_amdgcn_permlane16_swap(a, b, false, false);
  a = r[0]; b = r[1];
}
#endif

// ---------------- K1: emb = silu(t_emb) @ W_ada^T + b_ada  -> [2][4096] f32
__global__ void ada_kernel(const float* __restrict__ t_emb, const float* __restrict__ W_ada,
                           const float* __restrict__ b_ada, float* __restrict__ emb) {
  int w = threadIdx.x >> 6, lane = threadIdx.x & 63;
  int gid = blockIdx.x * 4 + w;          // 0..8191
  int b = gid >> 12, n = gid & 4095;
  const float* te = t_emb + (size_t)b * 1280;
  const float* wr = W_ada + (size_t)n * 1280;
  float acc = 0.f;
#pragma unroll
  for (int i = 0; i < 20; ++i) {
    int t = lane + i * 64;
    float x = te[t];
    float s = x / (1.f + __expf(-x));
    acc += s * wr[t];
  }
  acc = wred_sum(acc);
  if (lane == 0) emb[gid] = acc + b_ada[n];
}

// ---------------- K2: LayerNorm(ip) * (1+scale) + shift -> bf16 ip_n [1024][2048]
__global__ void ln_mod_kernel(const float* __restrict__ ip, const float* __restrict__ emb,
                              unsigned short* __restrict__ ipn) {
  int row = blockIdx.x;            // b*512 + l
  int b = row >> 9;
  const float* x = ip + (size_t)row * 2048;
  float xv[8];
  float s1 = 0.f, s2 = 0.f;
#pragma unroll
  for (int i = 0; i < 8; ++i) {
    float v = x[threadIdx.x + i * 256];
    xv[i] = v; s1 += v; s2 += v * v;
  }
  s1 = wred_sum(s1); s2 = wred_sum(s2);
  __shared__ float r1[4], r2[4];
  int w = threadIdx.x >> 6, lane = threadIdx.x & 63;
  if (lane == 0) { r1[w] = s1; r2[w] = s2; }
  __syncthreads();
  s1 = r1[0] + r1[1] + r1[2] + r1[3];
  s2 = r2[0] + r2[1] + r2[2] + r2[3];
  float mu = s1 * (1.f / 2048.f);
  float var = s2 * (1.f / 2048.f) - mu * mu;
  float rs = rsqrtf(var + 1e-6f);
  const float* sh = emb + (size_t)b * 4096;
  unsigned short* y = ipn + (size_t)row * 2048;
#pragma unroll
  for (int i = 0; i < 8; ++i) {
    int d = threadIdx.x + i * 256;
    float v = (xv[i] - mu) * rs;
    v = v * (1.f + sh[2048 + d]) + sh[d];
    y[d] = f2bf(v);
  }
}

// ---------------- K3: convert W_k_ip / W_v_ip fp32 -> bf16
struct us4 { unsigned short a, b, c, d; };
__global__ void cvtw_kernel(const float* __restrict__ wk, const float* __restrict__ wv,
                            unsigned short* __restrict__ wk16, unsigned short* __restrict__ wv16) {
  size_t i = ((size_t)blockIdx.x * 256 + threadIdx.x) * 4;
  float4 a = *(const float4*)(wk + i);
  float4 b = *(const float4*)(wv + i);
  us4 oa = { f2bf(a.x), f2bf(a.y), f2bf(a.z), f2bf(a.w) };
  us4 ob = { f2bf(b.x), f2bf(b.y), f2bf(b.z), f2bf(b.w) };
  *(us4*)(wk16 + i) = oa;
  *(us4*)(wv16 + i) = ob;
}

// ---------------- K4: C[1024,2048] = A[1024,2048]bf16 @ W[2048,2048]^T bf16 -> f32
__global__ __launch_bounds__(256) void proj_gemm(const unsigned short* __restrict__ A,
    const unsigned short* __restrict__ Wk, const unsigned short* __restrict__ Wv,
    float* __restrict__ Ck, float* __restrict__ Cv) {
  const unsigned short* Bm = blockIdx.z ? Wv : Wk;
  float* C = blockIdx.z ? Cv : Ck;
  int n0 = blockIdx.x * 64, m0 = blockIdx.y * 128;
  __shared__ __align__(16) unsigned short As[128 * 72];
  __shared__ __align__(16) unsigned short Bs[64 * 72];
  int tid = threadIdx.x, w = tid >> 6, lane = tid & 63, quad = lane >> 4, l16 = lane & 15;
  floatx4 acc[2][4];
#pragma unroll
  for (int i = 0; i < 2; ++i)
#pragma unroll
    for (int j = 0; j < 4; ++j) { floatx4 z = {0.f, 0.f, 0.f, 0.f}; acc[i][j] = z; }
  for (int kk = 0; kk < 2048; kk += 64) {
#pragma unroll
    for (int it = 0; it < 4; ++it) {
      int idx = tid + it * 256;
      int row = idx >> 3, chk = idx & 7;
      *(uint4*)&As[row * 72 + chk * 8] = *(const uint4*)&A[(size_t)(m0 + row) * 2048 + kk + chk * 8];
    }
#pragma unroll
    for (int it = 0; it < 2; ++it) {
      int idx = tid + it * 256;
      int row = idx >> 3, chk = idx & 7;
      *(uint4*)&Bs[row * 72 + chk * 8] = *(const uint4*)&Bm[(size_t)(n0 + row) * 2048 + kk + chk * 8];
    }
    __syncthreads();
#pragma unroll
    for (int c = 0; c < 2; ++c) {
      bf16x8 a0 = *(const bf16x8*)&As[(w * 32 + l16) * 72 + quad * 8 + c * 32];
      bf16x8 a1 = *(const bf16x8*)&As[(w * 32 + 16 + l16) * 72 + quad * 8 + c * 32];
#pragma unroll
      for (int nt = 0; nt < 4; ++nt) {
        bf16x8 bb = *(const bf16x8*)&Bs[(nt * 16 + l16) * 72 + quad * 8 + c * 32];
        acc[0][nt] = mfma32(a0, bb, acc[0][nt]);
        acc[1][nt] = mfma32(a1, bb, acc[1][nt]);
      }
    }
    __syncthreads();
  }
#pragma unroll
  for (int rt = 0; rt < 2; ++rt)
#pragma unroll
    for (int nt = 0; nt < 4; ++nt)
#pragma unroll
      for (int r = 0; r < 4; ++r)
        C[(size_t)(m0 + w * 32 + rt * 16 + quad * 4 + r) * 2048 + n0 + nt * 16 + l16] = acc[rt][nt][r];
}

// ---------------- K5: Kcat [bh][2560][128] (rms, 16B-chunk XOR-swizzled per row)
//                      Vrec [bh][mt=40][16 records][64 lanes][8 bf16]
//   V is emitted as ready-made PV A-fragments: record r=(dt*2+mc), lane
//   (quad,l16) holds V^T[dt*16+l16][mc*32+quad*8 .. +7]. attn reads one
//   coalesced 1-KB global load per (dt,mc) -- V never touches attn's LDS.
__global__ __launch_bounds__(256) void kv_build(const float* __restrict__ img_key, const float* __restrict__ img_value,
                         const float* __restrict__ ipk, const float* __restrict__ ipv,
                         const float* __restrict__ w_k, const float* __restrict__ w_ipk,
                         unsigned short* __restrict__ Kc, unsigned short* __restrict__ Vrec) {
  int bh = blockIdx.x;                 // 0..31
  int mt = blockIdx.y;                 // 0..39
  int b = bh >> 4, hh = bh & 15;
  int m0 = mt * 64;
  __shared__ __align__(16) unsigned short Vs[64 * 132];
  int tid = threadIdx.x;
  int mrow = tid >> 2, dq = tid & 3;   // 64 rows x 4 quarters of d
  int m = m0 + mrow;
  size_t base;
  const float* wsrc;
  const float *ksrc, *vsrc;
  if (m < 2048) {
    base = (size_t)(b * 2048 + m) * 2048 + hh * 128;
    ksrc = img_key + base; vsrc = img_value + base; wsrc = w_k;
  } else {
    base = (size_t)(b * 512 + (m - 2048)) * 2048 + hh * 128;
    ksrc = ipk + base; vsrc = ipv + base; wsrc = w_ipk;
  }
  // K: load 32 d-values, rms over 4 lanes sharing the row, write swizzled bf16
  float kvv[32]; float ss = 0.f;
  const float4* k4 = (const float4*)ksrc;
#pragma unroll
  for (int i = 0; i < 8; ++i) {
    float4 x = k4[dq * 8 + i];
    kvv[i * 4 + 0] = x.x; kvv[i * 4 + 1] = x.y; kvv[i * 4 + 2] = x.z; kvv[i * 4 + 3] = x.w;
    ss += x.x * x.x + x.y * x.y + x.z * x.z + x.w * x.w;
  }
  ss += __shfl_xor(ss, 1, 64);
  ss += __shfl_xor(ss, 2, 64);
  float rs = rsqrtf(ss * (1.f / 128.f) + 1e-6f);
  unsigned short kb[32];
#pragma unroll
  for (int j = 0; j < 32; ++j) kb[j] = f2bf(kvv[j] * rs * wsrc[dq * 32 + j]);
  uint4* kdst = (uint4*)&Kc[((size_t)bh * 2560 + m) * 128];
#pragma unroll
  for (int i = 0; i < 4; ++i) kdst[(dq * 4 + i) ^ (m & 7)] = ((const uint4*)kb)[i];
  // V: to LDS as bf16 [m][d] (stride 132), then frag-records out (coalesced)
  const float4* v4 = (const float4*)vsrc;
#pragma unroll
  for (int i = 0; i < 8; ++i) {
    float4 x = v4[dq * 8 + i];
    us4 p = { f2bf(x.x), f2bf(x.y), f2bf(x.z), f2bf(x.w) };
    *(us4*)&Vs[mrow * 132 + dq * 32 + i * 4] = p;
  }
  __syncthreads();
  // thread handles lane-slot (tid&63) of records r = (tid>>6) + 4*i
  int lslot = tid & 63;
  unsigned short* tb = Vrec + ((size_t)(bh * 40 + mt)) * 8192;
#pragma unroll
  for (int i = 0; i < 4; ++i) {
    int r = (tid >> 6) + 4 * i;          // 0..15 = dt*2+mc
    int dcol = (r >> 1) * 16 + (lslot & 15);
    int mrow2 = (r & 1) * 32 + (lslot >> 4) * 8;
    unsigned short ob[8];
#pragma unroll
    for (int j = 0; j < 8; ++j) ob[j] = Vs[(mrow2 + j) * 132 + dcol];
    *(uint4*)&tb[r * 512 + lslot * 8] = *(const uint4*)ob;
  }
}

// ---------------- K7: flash attention, transposed-S formulation.
// Round-5 fix: round 4's __launch_bounds__(256,4) capped VGPRs at 128 < the
// ~140 live state -> accumulator spill to scratch (WRITE_SIZE 32->417 MB,
// VGPR_Count 64, 2.5x regression). (256,3) gives a 168-VGPR budget: no
// spill, 3 blocks/CU (12 waves/CU, 1.5x round-3 TLP). V comes straight
// from global as pre-built A-frag records (1-KB coalesced load per
// (dt,mc)); only K is staged in LDS (double-buffered 2x16KB = 32 KB).
// QK^T runs per-32m-chunk to keep sacc live range at 16 regs. S^T = K*Q^T;
// P transposed in-register (permlane32/16 swaps) to the K=32 B-frag
// layout; O^T = Vrec * P.
__global__ __launch_bounds__(256, 3) void attn_kernel(const float* __restrict__ Qf,
    const float* __restrict__ w_q,
    const unsigned short* __restrict__ Kc, const unsigned short* __restrict__ Vrec,
    float* __restrict__ out) {
  const float SCL = 0.12751744f;   // (1/sqrt(128)) * log2(e)
  const float FM = 17.0f;          // fixed softmax max (score*SCL bounded by 16.4)
  // XCD-locality remap: XCD = blockIdx % 8 (round-robin dispatch)
  int n = blockIdx.x;              // 0..511
  int xcd = n & 7, jj = n >> 3;    // jj 0..63
  int bh = xcd * 4 + (jj >> 4);    // 4 consecutive bh per XCD
  int qt2 = jj & 15;               // 0..15, 128 q-rows each
  int b = bh >> 4, hh = bh & 15;
  int tid = threadIdx.x, w = tid >> 6, lane = tid & 63, quad = lane >> 4, l16 = lane & 15;
  int xr = l16 & 7;

  __shared__ __align__(16) unsigned char smem[32768];    // 2x Kt 16K

  int q0 = qt2 * 128;

  // ---- Q: load f32, RMS-norm, pack to B bf16 fragments (2 q-tiles/wave)
  bf16x8 aq[2][4];
#pragma unroll
  for (int qtl = 0; qtl < 2; ++qtl) {
    int qrow = q0 + w * 32 + qtl * 16 + l16;
    const float* src = Qf + ((size_t)(b * 2048 + qrow)) * 2048 + hh * 128;
    float xs[32]; float ss = 0.f;
#pragma unroll
    for (int c = 0; c < 4; ++c) {
      float4 a = *(const float4*)&src[quad * 8 + c * 32];
      float4 b2 = *(const float4*)&src[quad * 8 + c * 32 + 4];
      xs[c * 8 + 0] = a.x;  xs[c * 8 + 1] = a.y;  xs[c * 8 + 2] = a.z;  xs[c * 8 + 3] = a.w;
      xs[c * 8 + 4] = b2.x; xs[c * 8 + 5] = b2.y; xs[c * 8 + 6] = b2.z; xs[c * 8 + 7] = b2.w;
      ss += a.x * a.x + a.y * a.y + a.z * a.z + a.w * a.w
          + b2.x * b2.x + b2.y * b2.y + b2.z * b2.z + b2.w * b2.w;
    }
    ss += __shfl_xor(ss, 16, 64);
    ss += __shfl_xor(ss, 32, 64);
    float rs = rsqrtf(ss * (1.f / 128.f) + 1e-6f);
#pragma unroll
    for (int c = 0; c < 4; ++c) {
      float4 wa = *(const float4*)&w_q[quad * 8 + c * 32];
      float4 wb = *(const float4*)&w_q[quad * 8 + c * 32 + 4];
      union { unsigned int u[4]; bf16x8 v; } pk;
      pk.u[0] = pk_bf16(xs[c * 8 + 0] * rs * wa.x, xs[c * 8 + 1] * rs * wa.y);
      pk.u[1] = pk_bf16(xs[c * 8 + 2] * rs * wa.z, xs[c * 8 + 3] * rs * wa.w);
      pk.u[2] = pk_bf16(xs[c * 8 + 4] * rs * wb.x, xs[c * 8 + 5] * rs * wb.y);
      pk.u[3] = pk_bf16(xs[c * 8 + 6] * rs * wb.z, xs[c * 8 + 7] * rs * wb.w);
      aq[qtl][c] = pk.v;
    }
  }

  const unsigned short* Kb = Kc + (size_t)bh * 2560 * 128;
  const unsigned short* Vb = Vrec + (size_t)bh * 40 * 8192;

  floatx4 acc[2][8];
#pragma unroll
  for (int i = 0; i < 2; ++i)
#pragma unroll
    for (int j = 0; j < 8; ++j) { floatx4 z = {0.f, 0.f, 0.f, 0.f}; acc[i][j] = z; }
  float rsum[2] = {0.f, 0.f};

  int seg = w * 4;
  auto stage = [&](int buf, int t) {
    const unsigned short* Ksrc = Kb + (size_t)t * 8192;
    unsigned short* Kt = (unsigned short*)(smem + buf * 16384);
#pragma unroll
    for (int j = 0; j < 4; ++j) {
      int off = (seg + j) * 512 + lane * 8;
      dma16(Ksrc + off, Kt + (seg + j) * 512);
    }
  };

  stage(0, 0);
  __syncthreads();

  for (int t = 0; t < 40; ++t) {
    int cur = t & 1;
    if (t < 39) stage(cur ^ 1, t + 1);   // issue next tile's K loads
    const unsigned short* Kt = (const unsigned short*)(smem + cur * 16384);
    const unsigned short* Vr = Vb + (size_t)t * 8192;

    // S^T = K·Q^T per 32-m chunk; softmax+transpose immediately (sacc live = 16 regs)
    union { unsigned int u[4]; bf16x8 v; } pf[2][2];   // [mchunk][qtl]
#pragma unroll
    for (int mc = 0; mc < 2; ++mc) {
      floatx4 sacc[2][2];
#pragma unroll
      for (int i = 0; i < 2; ++i)
#pragma unroll
        for (int j = 0; j < 2; ++j) { floatx4 z = {0.f, 0.f, 0.f, 0.f}; sacc[i][j] = z; }
#pragma unroll
      for (int ms2 = 0; ms2 < 2; ++ms2) {
        int krow = ((mc * 2 + ms2) * 16 + l16) * 128;
#pragma unroll
        for (int c = 0; c < 4; ++c) {
          bf16x8 bk = *(const bf16x8*)&Kt[krow + ((quad + c * 4) ^ xr) * 8];
          sacc[ms2][0] = mfma32(bk, aq[0][c], sacc[ms2][0]);
          sacc[ms2][1] = mfma32(bk, aq[1][c], sacc[ms2][1]);
        }
      }
#pragma unroll
      for (int qtl = 0; qtl < 2; ++qtl) {
        float pA[4], pB[4];
#pragma unroll
        for (int r = 0; r < 4; ++r) {
          pA[r] = __builtin_amdgcn_exp2f(fmaf(sacc[0][qtl][r], SCL, -FM));
          pB[r] = __builtin_amdgcn_exp2f(fmaf(sacc[1][qtl][r], SCL, -FM));
        }
        rsum[qtl] += (pA[0] + pA[1]) + (pA[2] + pA[3])
                   + (pB[0] + pB[1]) + (pB[2] + pB[3]);
        // R_r@quad holds m-pair rho = 8*(r>>1) + 2*quad + (r&1)
        unsigned int R0 = pk_bf16(pA[0], pA[1]);
        unsigned int R1 = pk_bf16(pA[2], pA[3]);
        unsigned int R2 = pk_bf16(pB[0], pB[1]);
        unsigned int R3 = pk_bf16(pB[2], pB[3]);
#ifdef HAS_PLSWAP
        // transpose: target T_j@quad = rho 4*quad + j  (k = quad*8+2j,+1)
        p32sw(R0, R2);   // R0=(0,2,8,10)   R2=(4,6,12,14)
        p32sw(R1, R3);   // R1=(1,3,9,11)   R3=(5,7,13,15)
        p16sw(R0, R2);   // R0=(0,4,8,12)=T0  R2=(2,6,10,14)=T2
        p16sw(R1, R3);   // R1=(1,5,9,13)=T1  R3=(3,7,11,15)=T3
        pf[mc][qtl].u[0] = R0; pf[mc][qtl].u[1] = R1;
        pf[mc][qtl].u[2] = R2; pf[mc][qtl].u[3] = R3;
#else
        // fallback: T_j <- R_{2*(quad>>1)+(j&1)} @ lane (2*(quad&1)+(j>>1))*16+l16
        int base = ((quad & 1) * 2) * 16 + l16;
        int base2 = base + 16;
        unsigned int a0 = __shfl((int)R0, base, 64),  b0 = __shfl((int)R2, base, 64);
        unsigned int a1 = __shfl((int)R1, base, 64),  b1 = __shfl((int)R3, base, 64);
        unsigned int a2 = __shfl((int)R0, base2, 64), b2 = __shfl((int)R2, base2, 64);
        unsigned int a3 = __shfl((int)R1, base2, 64), b3 = __shfl((int)R3, base2, 64);
        bool hi = (quad >> 1) != 0;
        pf[mc][qtl].u[0] = hi ? b0 : a0;
        pf[mc][qtl].u[1] = hi ? b1 : a1;
        pf[mc][qtl].u[2] = hi ? b2 : a2;
        pf[mc][qtl].u[3] = hi ? b3 : a3;
#endif
      }
    }

    // O^T += V·P : A-frag = direct coalesced 1-KB record loads, K=32
#pragma unroll
    for (int dt = 0; dt < 8; ++dt) {
      bf16x8 va0 = *(const bf16x8*)&Vr[(dt * 2 + 0) * 512 + lane * 8];
      bf16x8 va1 = *(const bf16x8*)&Vr[(dt * 2 + 1) * 512 + lane * 8];
      acc[0][dt] = mfma32(va0, pf[0][0].v, acc[0][dt]);
      acc[1][dt] = mfma32(va0, pf[0][1].v, acc[1][dt]);
      acc[0][dt] = mfma32(va1, pf[1][0].v, acc[0][dt]);
      acc[1][dt] = mfma32(va1, pf[1][1].v, acc[1][dt]);
    }
    __syncthreads();   // drains vmcnt: next tile's K loads completed during compute
  }

  // ---- epilogue: rsum complete per wave after quad reduction; direct write
  rsum[0] += __shfl_xor(rsum[0], 16, 64); rsum[0] += __shfl_xor(rsum[0], 32, 64);
  rsum[1] += __shfl_xor(rsum[1], 16, 64); rsum[1] += __shfl_xor(rsum[1], 32, 64);
#pragma unroll
  for (int qtl = 0; qtl < 2; ++qtl) {
    float inv = 1.f / rsum[qtl];
    int qrow = q0 + w * 32 + qtl * 16 + l16;
    float* orow = out + ((size_t)(b * 2048 + qrow)) * 2048 + hh * 128;
#pragma unroll
    for (int dt = 0; dt < 8; ++dt) {
      floatx4 r = acc[qtl][dt] * inv;
      *(floatx4*)&orow[dt * 16 + quad * 4] = r;
    }
  }
}

extern "C" void kernel_launch(void* const* d_in, const int* in_sizes, int n_in,
                              void* d_out, int out_size, void* d_ws, size_t ws_size,
                              hipStream_t stream) {
  const float* ip    = (const float*)d_in[0];
  const float* q     = (const float*)d_in[1];
  const float* k     = (const float*)d_in[2];
  const float* v     = (const float*)d_in[3];
  const float* temb  = (const float*)d_in[4];
  const float* wada  = (const float*)d_in[5];
  const float* bada  = (const float*)d_in[6];
  const float* wkip  = (const float*)d_in[7];
  const float* wvip  = (const float*)d_in[8];
  const float* w_q   = (const float*)d_in[9];
  const float* w_k   = (const float*)d_in[10];
  const float* w_ipk = (const float*)d_in[11];
  float* out = (float*)d_out;
  char* ws = (char*)d_ws;

  // Lifetime-overlapped workspace layout (75.5 MB total):
  //   emb[0,32K) ipn[32K,4.2M) wk16[4.2M,12.6M) wv16[12.6M,21.0M)  (dead after proj_gemm)
  //   Kcat[16.7M,37.7M) Vrec[37.7M,58.7M)
  //   ipk[58.7M,67.1M) ipv[67.1M,75.5M)
  float* emb           = (float*)(ws + 0);
  unsigned short* ipn  = (unsigned short*)(ws + 32768);
  unsigned short* wk16 = (unsigned short*)(ws + 4227072);
  unsigned short* wv16 = (unsigned short*)(ws + 12615680);
  unsigned short* Kcat = (unsigned short*)(ws + 16777216);
  unsigned short* Vrec = (unsigned short*)(ws + 37748736);
  float* ipk           = (float*)(ws + 58720256);
  float* ipv           = (float*)(ws + 67108864);

  ada_kernel<<<dim3(2048), dim3(256), 0, stream>>>(temb, wada, bada, emb);
  ln_mod_kernel<<<dim3(1024), dim3(256), 0, stream>>>(ip, emb, ipn);
  cvtw_kernel<<<dim3(4096), dim3(256), 0, stream>>>(wkip, wvip, wk16, wv16);
  proj_gemm<<<dim3(32, 8, 2), dim3(256), 0, stream>>>(ipn, wk16, wv16, ipk, ipv);
  kv_build<<<dim3(32, 40), dim3(256), 0, stream>>>(k, v, ipk, ipv, w_k, w_ipk, Kcat, Vrec);
  attn_kernel<<<dim3(512), dim3(256), 0, stream>>>(q, w_q, Kcat, Vrec, out);
}

// Round 7
// 330.610 us; speedup vs baseline: 1.6853x; 1.2933x over previous
//
#include <hip/hip_runtime.h>
#include <hip/hip_bf16.h>

typedef __attribute__((ext_vector_type(8))) __bf16 bf16x8;
typedef __attribute__((ext_vector_type(2))) __bf16 bf16x2;
typedef __attribute__((ext_vector_type(4))) float floatx4;
typedef __attribute__((ext_vector_type(2))) unsigned int uint2v;

#define DEV static __device__ __forceinline__

typedef __attribute__((address_space(1))) const unsigned int gu32;
typedef __attribute__((address_space(3))) unsigned int lu32;

DEV void dma16(const void* g, void* l) {
  // async global->LDS, 16B/lane; LDS dst MUST be wave-uniform base (+lane*16 implicit)
  __builtin_amdgcn_global_load_lds((gu32*)g, (lu32*)l, 16, 0, 0);
}

DEV unsigned short f2bf(float f) {
  unsigned int u = __float_as_uint(f);
  u += 0x7fffu + ((u >> 16) & 1u);   // round-to-nearest-even
  return (unsigned short)(u >> 16);
}

DEV unsigned int pk_bf16(float a, float b) {
#if __has_builtin(__builtin_amdgcn_cvt_pk_bf16_f32)
  bf16x2 r = __builtin_amdgcn_cvt_pk_bf16_f32(a, b);
  union { bf16x2 v; unsigned int u; } c; c.v = r;
  return c.u;
#else
  return (unsigned int)f2bf(a) | ((unsigned int)f2bf(b) << 16);
#endif
}

DEV float wred_sum(float v) {
#pragma unroll
  for (int o = 32; o > 0; o >>= 1) v += __shfl_xor(v, o, 64);
  return v;
}

DEV floatx4 mfma32(bf16x8 a, bf16x8 b, floatx4 c) {
  return __builtin_amdgcn_mfma_f32_16x16x32_bf16(a, b, c, 0, 0, 0);
}

#if __has_builtin(__builtin_amdgcn_permlane32_swap) && __has_builtin(__builtin_amdgcn_permlane16_swap)
#define HAS_PLSWAP 1
DEV void p32sw(unsigned int& a, unsigned int& b) {
  uint2v r = __builtin_amdgcn_permlane32_swap(a, b, false, false);
  a = r[0]; b = r[1];
}
DEV void p16sw(unsigned int& a, unsigned int& b) {
  uint2v r = __builtin_amdgcn_permlane16_swap(a, b, false, false);
  a = r[0]; b = r[1];
}
#endif

// ---------------- K1: emb = silu(t_emb) @ W_ada^T + b_ada  -> [2][4096] f32
__global__ void ada_kernel(const float* __restrict__ t_emb, const float* __restrict__ W_ada,
                           const float* __restrict__ b_ada, float* __restrict__ emb) {
  int w = threadIdx.x >> 6, lane = threadIdx.x & 63;
  int gid = blockIdx.x * 4 + w;          // 0..8191
  int b = gid >> 12, n = gid & 4095;
  const float* te = t_emb + (size_t)b * 1280;
  const float* wr = W_ada + (size_t)n * 1280;
  float acc = 0.f;
#pragma unroll
  for (int i = 0; i < 20; ++i) {
    int t = lane + i * 64;
    float x = te[t];
    float s = x / (1.f + __expf(-x));
    acc += s * wr[t];
  }
  acc = wred_sum(acc);
  if (lane == 0) emb[gid] = acc + b_ada[n];
}

// ---------------- K2: LayerNorm(ip) * (1+scale) + shift -> bf16 ip_n [1024][2048]
// Output is chunk-swizzled for proj_gemm's global_load_lds staging: within
// each 64-element k-group, 16B chunk c is stored at c ^ (row & 7).
__global__ void ln_mod_kernel(const float* __restrict__ ip, const float* __restrict__ emb,
                              unsigned short* __restrict__ ipn) {
  int row = blockIdx.x;            // b*512 + l
  int b = row >> 9;
  int tid = threadIdx.x;
  const float* x = ip + (size_t)row * 2048;
  float xv[8];
  float s1 = 0.f, s2 = 0.f;
  {
    float4 x0 = *(const float4*)&x[tid * 8];
    float4 x1 = *(const float4*)&x[tid * 8 + 4];
    xv[0] = x0.x; xv[1] = x0.y; xv[2] = x0.z; xv[3] = x0.w;
    xv[4] = x1.x; xv[5] = x1.y; xv[6] = x1.z; xv[7] = x1.w;
#pragma unroll
    for (int i = 0; i < 8; ++i) { s1 += xv[i]; s2 += xv[i] * xv[i]; }
  }
  s1 = wred_sum(s1); s2 = wred_sum(s2);
  __shared__ float r1[4], r2[4];
  int w = tid >> 6, lane = tid & 63;
  if (lane == 0) { r1[w] = s1; r2[w] = s2; }
  __syncthreads();
  s1 = r1[0] + r1[1] + r1[2] + r1[3];
  s2 = r2[0] + r2[1] + r2[2] + r2[3];
  float mu = s1 * (1.f / 2048.f);
  float var = s2 * (1.f / 2048.f) - mu * mu;
  float rs = rsqrtf(var + 1e-6f);
  const float* sh = emb + (size_t)b * 4096;
  unsigned short* y = ipn + (size_t)row * 2048;
  unsigned short ob[8];
#pragma unroll
  for (int i = 0; i < 8; ++i) {
    int d = tid * 8 + i;
    float v = (xv[i] - mu) * rs;
    v = v * (1.f + sh[2048 + d]) + sh[d];
    ob[i] = f2bf(v);
  }
  int dst = (tid & ~7) | ((tid & 7) ^ (row & 7));
  *(uint4*)&y[dst * 8] = *(const uint4*)ob;
}

// ---------------- K3: convert W_k_ip / W_v_ip fp32 -> bf16 (chunk-swizzled, see K2)
__global__ void cvtw_kernel(const float* __restrict__ wk, const float* __restrict__ wv,
                            unsigned short* __restrict__ wk16, unsigned short* __restrict__ wv16) {
  int row = blockIdx.x, tid = threadIdx.x;     // one 2048-elem row per block
  size_t gi = (size_t)row * 2048 + tid * 8;
  int dst = (tid & ~7) | ((tid & 7) ^ (row & 7));
  size_t o = (size_t)row * 2048 + (size_t)dst * 8;
  float4 a0 = *(const float4*)(wk + gi), a1 = *(const float4*)(wk + gi + 4);
  float4 b0 = *(const float4*)(wv + gi), b1 = *(const float4*)(wv + gi + 4);
  unsigned short oa[8] = { f2bf(a0.x), f2bf(a0.y), f2bf(a0.z), f2bf(a0.w),
                           f2bf(a1.x), f2bf(a1.y), f2bf(a1.z), f2bf(a1.w) };
  unsigned short ob[8] = { f2bf(b0.x), f2bf(b0.y), f2bf(b0.z), f2bf(b0.w),
                           f2bf(b1.x), f2bf(b1.y), f2bf(b1.z), f2bf(b1.w) };
  *(uint4*)(wk16 + o) = *(const uint4*)oa;
  *(uint4*)(wv16 + o) = *(const uint4*)ob;
}

// ---------------- K4: C[1024,2048] = A[1024,2048]bf16 @ W[2048,2048]^T bf16 -> f32
// m97-pattern staging: global_load_lds (16B/lane) of pre-swizzled operands,
// double-buffered, ONE barrier per K-step. LDS 48 KB (As 16K + Bs 8K, x2).
// LDS dst is the wave-uniform segment base; HW adds lane*16. LDS layout:
// [row][chunkpos][16B], chunkpos = orig_chunk ^ (row&7). Fragment reads at
// chunk ^ (l16&7): 2-way bank conflict (free).
__global__ __launch_bounds__(256) void proj_gemm(const unsigned short* __restrict__ A,
    const unsigned short* __restrict__ Wk, const unsigned short* __restrict__ Wv,
    float* __restrict__ Ck, float* __restrict__ Cv) {
  const unsigned short* Bm = blockIdx.z ? Wv : Wk;
  float* C = blockIdx.z ? Cv : Ck;
  int n0 = blockIdx.x * 64, m0 = blockIdx.y * 128;
  __shared__ __align__(16) unsigned char smem[49152];   // 2x (As 16K | Bs 8K)
  int tid = threadIdx.x, w = tid >> 6, lane = tid & 63, quad = lane >> 4, l16 = lane & 15;
  int xr = l16 & 7;
  floatx4 acc[2][4];
#pragma unroll
  for (int i = 0; i < 2; ++i)
#pragma unroll
    for (int j = 0; j < 4; ++j) { floatx4 z = {0.f, 0.f, 0.f, 0.f}; acc[i][j] = z; }

  const char* Abase = (const char*)A + (size_t)m0 * 4096;
  const char* Bbase = (const char*)Bm + (size_t)n0 * 4096;
  auto stage = [&](int buf, int kk) {   // kk in elements
    char* As = (char*)(smem + buf * 24576);
    char* Bs = (char*)(smem + buf * 24576 + 16384);
#pragma unroll
    for (int j = 0; j < 4; ++j) {
      int idx = (w * 4 + j) * 64 + lane;           // A chunk 0..1023: row=idx>>3, c=idx&7
      dma16(Abase + (size_t)(idx >> 3) * 4096 + kk * 2 + (idx & 7) * 16,
            As + (w * 4 + j) * 1024);              // uniform base; +lane*16 implicit
    }
#pragma unroll
    for (int j = 0; j < 2; ++j) {
      int idx = (w * 2 + j) * 64 + lane;           // B chunk 0..511
      dma16(Bbase + (size_t)(idx >> 3) * 4096 + kk * 2 + (idx & 7) * 16,
            Bs + (w * 2 + j) * 1024);              // uniform base; +lane*16 implicit
    }
  };

  stage(0, 0);
  __syncthreads();
  for (int t = 0; t < 32; ++t) {
    int cur = t & 1;
    if (t < 31) stage(cur ^ 1, (t + 1) * 64);      // prefetch next K-tile
    const unsigned short* As = (const unsigned short*)(smem + cur * 24576);
    const unsigned short* Bs = (const unsigned short*)(smem + cur * 24576 + 16384);
#pragma unroll
    for (int cc = 0; cc < 2; ++cc) {
      int pc = ((quad + 4 * cc) ^ xr) * 8;         // swizzled chunk -> element offset
      bf16x8 a0 = *(const bf16x8*)&As[(w * 32 + l16) * 64 + pc];
      bf16x8 a1 = *(const bf16x8*)&As[(w * 32 + 16 + l16) * 64 + pc];
#pragma unroll
      for (int nt = 0; nt < 4; ++nt) {
        bf16x8 bb = *(const bf16x8*)&Bs[(nt * 16 + l16) * 64 + pc];
        acc[0][nt] = mfma32(a0, bb, acc[0][nt]);
        acc[1][nt] = mfma32(a1, bb, acc[1][nt]);
      }
    }
    __syncthreads();   // drains vmcnt: next tile's loads completed during compute
  }
#pragma unroll
  for (int rt = 0; rt < 2; ++rt)
#pragma unroll
    for (int nt = 0; nt < 4; ++nt)
#pragma unroll
      for (int r = 0; r < 4; ++r)
        C[(size_t)(m0 + w * 32 + rt * 16 + quad * 4 + r) * 2048 + n0 + nt * 16 + l16] = acc[rt][nt][r];
}

// ---------------- K5: Kcat [bh][2560][128] (rms, 16B-chunk XOR-swizzled per row)
//                      VtT  [bh][mt=40][128 d][64 m] (transposed tiles, XOR-swizzled)
struct us4 { unsigned short a, b, c, d; };
__global__ __launch_bounds__(256) void kv_build(const float* __restrict__ img_key, const float* __restrict__ img_value,
                         const float* __restrict__ ipk, const float* __restrict__ ipv,
                         const float* __restrict__ w_k, const float* __restrict__ w_ipk,
                         unsigned short* __restrict__ Kc, unsigned short* __restrict__ VtT) {
  int bh = blockIdx.x;                 // 0..31
  int mt = blockIdx.y;                 // 0..39
  int b = bh >> 4, hh = bh & 15;
  int m0 = mt * 64;
  __shared__ __align__(16) unsigned short Vs[64 * 132];
  int tid = threadIdx.x;
  int mrow = tid >> 2, dq = tid & 3;   // 64 rows x 4 quarters of d
  int m = m0 + mrow;
  size_t base;
  const float* wsrc;
  const float *ksrc, *vsrc;
  if (m < 2048) {
    base = (size_t)(b * 2048 + m) * 2048 + hh * 128;
    ksrc = img_key + base; vsrc = img_value + base; wsrc = w_k;
  } else {
    base = (size_t)(b * 512 + (m - 2048)) * 2048 + hh * 128;
    ksrc = ipk + base; vsrc = ipv + base; wsrc = w_ipk;
  }
  // K: load 32 d-values, rms over 4 lanes sharing the row, write swizzled bf16
  float kvv[32]; float ss = 0.f;
  const float4* k4 = (const float4*)ksrc;
#pragma unroll
  for (int i = 0; i < 8; ++i) {
    float4 x = k4[dq * 8 + i];
    kvv[i * 4 + 0] = x.x; kvv[i * 4 + 1] = x.y; kvv[i * 4 + 2] = x.z; kvv[i * 4 + 3] = x.w;
    ss += x.x * x.x + x.y * x.y + x.z * x.z + x.w * x.w;
  }
  ss += __shfl_xor(ss, 1, 64);
  ss += __shfl_xor(ss, 2, 64);
  float rs = rsqrtf(ss * (1.f / 128.f) + 1e-6f);
  unsigned short kb[32];
#pragma unroll
  for (int j = 0; j < 32; ++j) kb[j] = f2bf(kvv[j] * rs * wsrc[dq * 32 + j]);
  uint4* kdst = (uint4*)&Kc[((size_t)bh * 2560 + m) * 128];
#pragma unroll
  for (int i = 0; i < 4; ++i) kdst[(dq * 4 + i) ^ (m & 7)] = ((const uint4*)kb)[i];
  // V: to LDS as bf16 [m][d] (stride 132), then transposed swizzled tile out
  const float4* v4 = (const float4*)vsrc;
#pragma unroll
  for (int i = 0; i < 8; ++i) {
    float4 x = v4[dq * 8 + i];
    us4 p = { f2bf(x.x), f2bf(x.y), f2bf(x.z), f2bf(x.w) };
    *(us4*)&Vs[mrow * 132 + dq * 32 + i * 4] = p;
  }
  __syncthreads();
  int d = tid >> 1, half = tid & 1;
  unsigned short ob[32];
#pragma unroll
  for (int j = 0; j < 32; ++j) ob[j] = Vs[(half * 32 + j) * 132 + d];
  uint4* vdst = (uint4*)&VtT[((size_t)(bh * 40 + mt)) * 8192 + d * 64];
#pragma unroll
  for (int i = 0; i < 4; ++i) vdst[(half * 4 + i) ^ (d & 7)] = ((const uint4*)ob)[i];
}

// ---------------- K7: flash attention, transposed-S formulation (round-3 best:
// 116 us). 128 q-rows per block; 4 waves split by q only; each wave computes
// S over all 64 m (4 m-subtiles), softmax+transpose per 32-m chunk, PV
// accumulates both chunks. K and V staged via global_load_lds, double-
// buffered (64 KB), one barrier per tile. P transposed in-register
// (permlane32/16 swaps) to the K=32 B-frag layout; O^T = V^T*P.
__global__ __launch_bounds__(256, 2) void attn_kernel(const float* __restrict__ Qf,
    const float* __restrict__ w_q,
    const unsigned short* __restrict__ Kc, const unsigned short* __restrict__ VtT,
    float* __restrict__ out) {
  const float SCL = 0.12751744f;   // (1/sqrt(128)) * log2(e)
  const float FM = 17.0f;          // fixed softmax max (score*SCL bounded by 16.4)
  // XCD-locality remap: XCD = blockIdx % 8 (round-robin dispatch)
  int n = blockIdx.x;              // 0..511
  int xcd = n & 7, jj = n >> 3;    // jj 0..63
  int bh = xcd * 4 + (jj >> 4);    // 4 consecutive bh per XCD
  int qt2 = jj & 15;               // 0..15, 128 q-rows each
  int b = bh >> 4, hh = bh & 15;
  int tid = threadIdx.x, w = tid >> 6, lane = tid & 63, quad = lane >> 4, l16 = lane & 15;
  int xr = l16 & 7;

  __shared__ __align__(16) unsigned char smem[65536];    // 2x (Kt 16K | Vs 16K)

  int q0 = qt2 * 128;

  // ---- Q: load f32, RMS-norm, pack to B bf16 fragments (2 q-tiles/wave)
  bf16x8 aq[2][4];
#pragma unroll
  for (int qtl = 0; qtl < 2; ++qtl) {
    int qrow = q0 + w * 32 + qtl * 16 + l16;
    const float* src = Qf + ((size_t)(b * 2048 + qrow)) * 2048 + hh * 128;
    float xs[32]; float ss = 0.f;
#pragma unroll
    for (int c = 0; c < 4; ++c) {
      float4 a = *(const float4*)&src[quad * 8 + c * 32];
      float4 b2 = *(const float4*)&src[quad * 8 + c * 32 + 4];
      xs[c * 8 + 0] = a.x;  xs[c * 8 + 1] = a.y;  xs[c * 8 + 2] = a.z;  xs[c * 8 + 3] = a.w;
      xs[c * 8 + 4] = b2.x; xs[c * 8 + 5] = b2.y; xs[c * 8 + 6] = b2.z; xs[c * 8 + 7] = b2.w;
      ss += a.x * a.x + a.y * a.y + a.z * a.z + a.w * a.w
          + b2.x * b2.x + b2.y * b2.y + b2.z * b2.z + b2.w * b2.w;
    }
    ss += __shfl_xor(ss, 16, 64);
    ss += __shfl_xor(ss, 32, 64);
    float rs = rsqrtf(ss * (1.f / 128.f) + 1e-6f);
#pragma unroll
    for (int c = 0; c < 4; ++c) {
      float4 wa = *(const float4*)&w_q[quad * 8 + c * 32];
      float4 wb = *(const float4*)&w_q[quad * 8 + c * 32 + 4];
      union { unsigned int u[4]; bf16x8 v; } pk;
      pk.u[0] = pk_bf16(xs[c * 8 + 0] * rs * wa.x, xs[c * 8 + 1] * rs * wa.y);
      pk.u[1] = pk_bf16(xs[c * 8 + 2] * rs * wa.z, xs[c * 8 + 3] * rs * wa.w);
      pk.u[2] = pk_bf16(xs[c * 8 + 4] * rs * wb.x, xs[c * 8 + 5] * rs * wb.y);
      pk.u[3] = pk_bf16(xs[c * 8 + 6] * rs * wb.z, xs[c * 8 + 7] * rs * wb.w);
      aq[qtl][c] = pk.v;
    }
  }

  const unsigned short* Kb = Kc + (size_t)bh * 2560 * 128;
  const unsigned short* Vb = VtT + (size_t)bh * 40 * 8192;

  floatx4 acc[2][8];
#pragma unroll
  for (int i = 0; i < 2; ++i)
#pragma unroll
    for (int j = 0; j < 8; ++j) { floatx4 z = {0.f, 0.f, 0.f, 0.f}; acc[i][j] = z; }
  float rsum[2] = {0.f, 0.f};

  int seg = w * 4;
  auto stage = [&](int buf, int t) {
    const unsigned short* Ksrc = Kb + (size_t)t * 8192;
    const unsigned short* Vsrc = Vb + (size_t)t * 8192;
    unsigned short* Kt = (unsigned short*)(smem + buf * 32768);
    unsigned short* Vd = (unsigned short*)(smem + buf * 32768 + 16384);
#pragma unroll
    for (int j = 0; j < 4; ++j) {
      int off = (seg + j) * 512 + lane * 8;
      dma16(Ksrc + off, Kt + (seg + j) * 512);
      dma16(Vsrc + off, Vd + (seg + j) * 512);
    }
  };

  stage(0, 0);
  __syncthreads();

  for (int t = 0; t < 40; ++t) {
    int cur = t & 1;
    if (t < 39) stage(cur ^ 1, t + 1);   // issue next tile's loads (overlap with compute)
    const unsigned short* Kt = (const unsigned short*)(smem + cur * 32768);
    const unsigned short* Vs = (const unsigned short*)(smem + cur * 32768 + 16384);

    // S^T = K·Q^T: 4 m-subtiles x 2 q-tiles per wave
    floatx4 sacc[4][2];
#pragma unroll
    for (int ms = 0; ms < 4; ++ms)
#pragma unroll
      for (int j = 0; j < 2; ++j) { floatx4 z = {0.f, 0.f, 0.f, 0.f}; sacc[ms][j] = z; }
#pragma unroll
    for (int ms = 0; ms < 4; ++ms) {
      int krow = (ms * 16 + l16) * 128;
#pragma unroll
      for (int c = 0; c < 4; ++c) {
        bf16x8 bk = *(const bf16x8*)&Kt[krow + ((quad + c * 4) ^ xr) * 8];
        sacc[ms][0] = mfma32(bk, aq[0][c], sacc[ms][0]);
        sacc[ms][1] = mfma32(bk, aq[1][c], sacc[ms][1]);
      }
    }

    // softmax -> P packed bf16, then 4x4 cross-quad word transpose to the
    // K=32 B-frag layout, per 32-m chunk (mc): words from msub 2mc, 2mc+1
    union { unsigned int u[4]; bf16x8 v; } pf[2][2];   // [mchunk][qtl]
#pragma unroll
    for (int mc = 0; mc < 2; ++mc) {
#pragma unroll
      for (int qtl = 0; qtl < 2; ++qtl) {
        float pA[4], pB[4];
#pragma unroll
        for (int r = 0; r < 4; ++r) {
          pA[r] = __builtin_amdgcn_exp2f(fmaf(sacc[mc * 2][qtl][r], SCL, -FM));
          pB[r] = __builtin_amdgcn_exp2f(fmaf(sacc[mc * 2 + 1][qtl][r], SCL, -FM));
        }
        rsum[qtl] += (pA[0] + pA[1]) + (pA[2] + pA[3])
                   + (pB[0] + pB[1]) + (pB[2] + pB[3]);
        // R_r@quad holds m-pair rho = 8*(r>>1) + 2*quad + (r&1)
        unsigned int R0 = pk_bf16(pA[0], pA[1]);
        unsigned int R1 = pk_bf16(pA[2], pA[3]);
        unsigned int R2 = pk_bf16(pB[0], pB[1]);
        unsigned int R3 = pk_bf16(pB[2], pB[3]);
#ifdef HAS_PLSWAP
        // transpose: target T_j@quad = rho 4*quad + j  (k = quad*8+2j,+1)
        p32sw(R0, R2);   // R0=(0,2,8,10)   R2=(4,6,12,14)
        p32sw(R1, R3);   // R1=(1,3,9,11)   R3=(5,7,13,15)
        p16sw(R0, R2);   // R0=(0,4,8,12)=T0  R2=(2,6,10,14)=T2
        p16sw(R1, R3);   // R1=(1,5,9,13)=T1  R3=(3,7,11,15)=T3
        pf[mc][qtl].u[0] = R0; pf[mc][qtl].u[1] = R1;
        pf[mc][qtl].u[2] = R2; pf[mc][qtl].u[3] = R3;
#else
        // fallback: T_j <- R_{2*(quad>>1)+(j&1)} @ lane (2*(quad&1)+(j>>1))*16+l16
        int base = ((quad & 1) * 2) * 16 + l16;
        int base2 = base + 16;
        unsigned int a0 = __shfl((int)R0, base, 64),  b0 = __shfl((int)R2, base, 64);
        unsigned int a1 = __shfl((int)R1, base, 64),  b1 = __shfl((int)R3, base, 64);
        unsigned int a2 = __shfl((int)R0, base2, 64), b2 = __shfl((int)R2, base2, 64);
        unsigned int a3 = __shfl((int)R1, base2, 64), b3 = __shfl((int)R3, base2, 64);
        bool hi = (quad >> 1) != 0;
        pf[mc][qtl].u[0] = hi ? b0 : a0;
        pf[mc][qtl].u[1] = hi ? b1 : a1;
        pf[mc][qtl].u[2] = hi ? b2 : a2;
        pf[mc][qtl].u[3] = hi ? b3 : a3;
#endif
      }
    }

    // O^T += V^T·P : A-frag = V^T b128 reads (shared across q-tiles), K=32
#pragma unroll
    for (int dt = 0; dt < 8; ++dt) {
      int vrow = (dt * 16 + l16) * 64;
#pragma unroll
      for (int mc = 0; mc < 2; ++mc) {
        bf16x8 va = *(const bf16x8*)&Vs[vrow + ((mc * 4 + quad) ^ xr) * 8];
        acc[0][dt] = mfma32(va, pf[mc][0].v, acc[0][dt]);
        acc[1][dt] = mfma32(va, pf[mc][1].v, acc[1][dt]);
      }
    }
    __syncthreads();   // drains vmcnt: next tile's loads completed during compute
  }

  // ---- epilogue: rsum complete per wave after quad reduction; direct write
  rsum[0] += __shfl_xor(rsum[0], 16, 64); rsum[0] += __shfl_xor(rsum[0], 32, 64);
  rsum[1] += __shfl_xor(rsum[1], 16, 64); rsum[1] += __shfl_xor(rsum[1], 32, 64);
#pragma unroll
  for (int qtl = 0; qtl < 2; ++qtl) {
    float inv = 1.f / rsum[qtl];
    int qrow = q0 + w * 32 + qtl * 16 + l16;
    float* orow = out + ((size_t)(b * 2048 + qrow)) * 2048 + hh * 128;
#pragma unroll
    for (int dt = 0; dt < 8; ++dt) {
      floatx4 r = acc[qtl][dt] * inv;
      *(floatx4*)&orow[dt * 16 + quad * 4] = r;
    }
  }
}

extern "C" void kernel_launch(void* const* d_in, const int* in_sizes, int n_in,
                              void* d_out, int out_size, void* d_ws, size_t ws_size,
                              hipStream_t stream) {
  const float* ip    = (const float*)d_in[0];
  const float* q     = (const float*)d_in[1];
  const float* k     = (const float*)d_in[2];
  const float* v     = (const float*)d_in[3];
  const float* temb  = (const float*)d_in[4];
  const float* wada  = (const float*)d_in[5];
  const float* bada  = (const float*)d_in[6];
  const float* wkip  = (const float*)d_in[7];
  const float* wvip  = (const float*)d_in[8];
  const float* w_q   = (const float*)d_in[9];
  const float* w_k   = (const float*)d_in[10];
  const float* w_ipk = (const float*)d_in[11];
  float* out = (float*)d_out;
  char* ws = (char*)d_ws;

  // Lifetime-overlapped workspace layout (75.5 MB total):
  //   emb[0,32K) ipn[32K,4.2M) wk16[4.2M,12.6M) wv16[12.6M,21.0M)  (dead after proj_gemm)
  //   Kcat[16.7M,37.7M) VtT[37.7M,58.7M)
  //   ipk[58.7M,67.1M) ipv[67.1M,75.5M)
  float* emb           = (float*)(ws + 0);
  unsigned short* ipn  = (unsigned short*)(ws + 32768);
  unsigned short* wk16 = (unsigned short*)(ws + 4227072);
  unsigned short* wv16 = (unsigned short*)(ws + 12615680);
  unsigned short* Kcat = (unsigned short*)(ws + 16777216);
  unsigned short* VtT  = (unsigned short*)(ws + 37748736);
  float* ipk           = (float*)(ws + 58720256);
  float* ipv           = (float*)(ws + 67108864);

  ada_kernel<<<dim3(2048), dim3(256), 0, stream>>>(temb, wada, bada, emb);
  ln_mod_kernel<<<dim3(1024), dim3(256), 0, stream>>>(ip, emb, ipn);
  cvtw_kernel<<<dim3(2048), dim3(256), 0, stream>>>(wkip, wvip, wk16, wv16);
  proj_gemm<<<dim3(32, 8, 2), dim3(256), 0, stream>>>(ipn, wk16, wv16, ipk, ipv);
  kv_build<<<dim3(32, 40), dim3(256), 0, stream>>>(k, v, ipk, ipv, w_k, w_ipk, Kcat, VtT);
  attn_kernel<<<dim3(512), dim3(256), 0, stream>>>(q, w_q, Kcat, VtT, out);
}